// Round 8
// baseline (1114.650 us; speedup 1.0000x reference)
//
#include <hip/hip_runtime.h>
#include <math.h>
#include <stdint.h>

#define T_   512
#define H_   1024
#define I_   512
#define E_   64
#define K_   6
#define G_   8
#define TG_  3
#define EB_  80      // 64 routed + 16 shared-expert (half x token-eighth) blocks

typedef _Float16 h8 __attribute__((ext_vector_type(8)));
typedef _Float16 h4v __attribute__((ext_vector_type(4)));
typedef float    f4 __attribute__((ext_vector_type(4)));

// ------- router + xh-prep + pseudo-init + wrow table (fused, verified) --
__global__ __launch_bounds__(64) void router_k(
    const float* __restrict__ x, const float* __restrict__ gw,
    int* __restrict__ cnt, int* __restrict__ tlist,
    float* __restrict__ wrow, _Float16* __restrict__ xh)
{
  const int t   = blockIdx.x;
  const int tid = threadIdx.x;
  __shared__ float sx[H_];
  __shared__ float sc[E_];

  for (int h4 = tid; h4 < H_/4; h4 += 64)
    ((float4*)sx)[h4] = ((const float4*)(x + (size_t)t*H_))[h4];
  __syncthreads();

  for (int h4 = tid; h4 < H_/4; h4 += 64) {
    float4 v = ((const float4*)sx)[h4];
    h4v o = { (_Float16)v.x, (_Float16)v.y, (_Float16)v.z, (_Float16)v.w };
    *(h4v*)(xh + (size_t)t*H_ + h4*4) = o;
  }
  if (t < 16) {
    int s  = t*64 + tid;                      // 0..1023
    int e  = 64 + (s >> 9);
    int tt = s & 511;
    tlist[e*T_ + tt] = (tt << 13) | (3072 + s);
    wrow[3072 + s] = 1.0f;
    if (s == 0) { cnt[64] = T_; cnt[65] = T_; }
  }

  const float* wr = gw + (size_t)tid * H_;
  float acc = 0.f;
  for (int h = 0; h < H_; h += 4) {
    float4 xv = *(const float4*)(sx + h);
    float4 wv = *(const float4*)(wr + h);
    acc = fmaf(xv.x, wv.x, acc); acc = fmaf(xv.y, wv.y, acc);
    acc = fmaf(xv.z, wv.z, acc); acc = fmaf(xv.w, wv.w, acc);
  }
  sc[tid] = 1.f / (1.f + expf(-acc));
  __syncthreads();

  if (tid == 0) {
    float gs[G_];
    #pragma unroll
    for (int g = 0; g < G_; g++) {
      float m = sc[g*8];
      #pragma unroll
      for (int j = 1; j < 8; j++) m = fmaxf(m, sc[g*8+j]);
      gs[g] = m;
    }
    unsigned gp = 0;
    for (int r = 0; r < TG_; r++) {
      int best = 0; float bv = -1e30f;
      for (int g = 0; g < G_; g++)
        if (!((gp >> g) & 1) && gs[g] > bv) { bv = gs[g]; best = g; }
      gp |= 1u << best;
    }
    int   eidx[K_]; float ew[K_];
    unsigned long long em = 0ull;
    float wsum = 0.f;
    for (int r = 0; r < K_; r++) {
      int best = 0; float bv = -1e30f;
      for (int e = 0; e < E_; e++) {
        if (!((gp >> (e >> 3)) & 1)) continue;
        if ((em >> e) & 1ull) continue;
        if (sc[e] > bv) { bv = sc[e]; best = e; }
      }
      em |= 1ull << best; eidx[r] = best; ew[r] = bv; wsum += bv;
    }
    const float inv = 2.5f / (wsum + 1e-20f);
    for (int r = 0; r < K_; r++) {
      int e = eidx[r];
      int pos = atomicAdd(&cnt[e], 1);
      tlist[e*T_ + pos] = (t << 13) | (t*K_ + r);   // row = t*6+rank
      wrow[t*K_ + r] = ew[r] * inv;
    }
  }
}

// ---- expert-block descriptor: eb<64 -> routed; eb>=64 -> shared slice ---
__device__ __forceinline__ void eb_decode(int eb, const int* cnt,
                                          int& e, int& lo, int& hi) {
  if (eb < E_) { e = eb; lo = 0; hi = cnt[e]; }
  else { int q = (eb - E_) & 7; e = E_ + ((eb - E_) >> 3); lo = q*64; hi = lo + 64; }
}

// two int4 (8 int32 weights) -> f16 fragment with scale folded (verified)
__device__ __forceinline__ h8 cvt8(int4 a, int4 b, float s) {
  union { _Float16 f[8]; h8 v; } t;
  t.f[0]=(_Float16)((float)a.x*s); t.f[1]=(_Float16)((float)a.y*s);
  t.f[2]=(_Float16)((float)a.z*s); t.f[3]=(_Float16)((float)a.w*s);
  t.f[4]=(_Float16)((float)b.x*s); t.f[5]=(_Float16)((float)b.y*s);
  t.f[6]=(_Float16)((float)b.z*s); t.f[7]=(_Float16)((float)b.w*s);
  return t.v;
}

// 8 int regs -> f16 fragment with scale folded (static unroll)
__device__ __forceinline__ h8 cvt8s(const int* w, float s) {
  union { _Float16 f[8]; h8 v; } t;
  #pragma unroll
  for (int j = 0; j < 8; j++) t.f[j] = (_Float16)((float)w[j]*s);
  return t.v;
}

// counted positional wait; sched_barrier pins loads into their region
#define WAITN(N) do { asm volatile("s_waitcnt vmcnt(" #N ")" ::: "memory"); \
                      __builtin_amdgcn_sched_barrier(0); } while (0)

// ---------------- gate+up MFMA: hmid[row, bi*16..+16) -------------------
// BARRIER-FREE register-direct K-loop (r0 structure) x fine-tile grid:
// grid 32x80 = 2560 blocks x 4 waves (wave = 16-tok subtile), bounds
// (256,6) -> 24 waves/CU resident, free-running (no s_barrier in K-loop;
// per-wave BW 0.68 GB/s in r0 vs 0.23 barrier-synced r7). Each lane loads
// its B-frags directly: Wg/Wu[irow=bi*16+mr][kt*32+quad*8..+8] = 2x int4
// per matrix (wave instr = 16 rows x 128B, clean chunks), cvt in regs.
// 2-deep ring, counted vmcnt(5) (5 loads/step), tail 5/0. W-loads are
// identical across the 4 waves -> L1/L2 served, HBM unique.
#define NKT_G 32

#define GU_LD(SLOT, KT)                                                       \
  do {                                                                        \
    Wg[SLOT][0] = *(const int4*)(wsg + (KT)*32);                              \
    Wg[SLOT][1] = *(const int4*)(wsg + (KT)*32 + 4);                          \
    Wu[SLOT][0] = *(const int4*)(wsu + (KT)*32);                              \
    Wu[SLOT][1] = *(const int4*)(wsu + (KT)*32 + 4);                          \
    Aa[SLOT]    = *(const h8*)(ax + (KT)*32);                                 \
  } while (0)

#define GU_CMP(SLOT, KT)                                                      \
  do {                                                                        \
    h8 bg = cvt8(Wg[SLOT][0], Wg[SLOT][1], sgp[sib8 + ((KT)>>2)]);            \
    h8 bu = cvt8(Wu[SLOT][0], Wu[SLOT][1], sup[sib8 + ((KT)>>2)]);            \
    accg = __builtin_amdgcn_mfma_f32_16x16x32_f16(Aa[SLOT], bg, accg, 0,0,0); \
    accu = __builtin_amdgcn_mfma_f32_16x16x32_f16(Aa[SLOT], bu, accu, 0,0,0); \
  } while (0)

#define GU_STEP(KT) do { WAITN(5); GU_CMP((KT)&1, KT); GU_LD((KT)&1, (KT)+2); } while (0)

__global__ __launch_bounds__(256, 6) void gateup_k(
    const _Float16* __restrict__ xh,
    const int* __restrict__ wg, const float* __restrict__ sg,
    const int* __restrict__ wu, const float* __restrict__ su,
    const int* __restrict__ shwg, const float* __restrict__ shsg,
    const int* __restrict__ shwu, const float* __restrict__ shsu,
    const int* __restrict__ cnt, const int* __restrict__ tlist,
    const float* __restrict__ wrow,
    _Float16* __restrict__ hmid)
{
  const int bi = blockIdx.x;                  // i-chunk of 16 (0..31)
  const int eb = blockIdx.y;
  int e, lo, hi;
  eb_decode(eb, cnt, e, lo, hi);
  if (hi <= lo) return;

  const int tid  = threadIdx.x;
  const int lane = tid & 63;
  const int wv   = tid >> 6;                  // token subtile (16 tok)
  const int mr   = lane & 15;
  const int quad = lane >> 4;

  const int *wgb, *wub; const float *sgp, *sup; int sib8;
  if (e < E_) {
    wgb = wg + (size_t)e*I_*H_;  wub = wu + (size_t)e*I_*H_;
    sgp = sg + e*32;  sup = su + e*32;  sib8 = (bi >> 3)*8;
  } else {
    int hf = e - E_;
    wgb = shwg + (size_t)hf*512*H_;  wub = shwu + (size_t)hf*512*H_;
    sgp = shsg;  sup = shsu;  sib8 = (hf*4 + (bi >> 3))*8;
  }

  const int irow = bi*16 + mr;                // this lane's B row (i)
  const int* wsg = wgb + (size_t)irow*H_ + quad*8;
  const int* wsu = wub + (size_t)irow*H_ + quad*8;

  __shared__ int stok[64]; __shared__ int srw[64]; __shared__ float swt[64];

  int4 Wg[2][2], Wu[2][2];
  h8   Aa[2];

  for (int base = lo; base < hi; base += 64) {
    __syncthreads();
    if (tid < 64) {
      int slot = base + tid;
      if (slot < hi) {
        int ent = tlist[e*T_ + slot];
        stok[tid] = ent >> 13; srw[tid] = ent & 8191;
        swt[tid]  = wrow[ent & 8191];
      } else { stok[tid] = -1; srw[tid] = 0; swt[tid] = 0.f; }
    }
    __syncthreads();                          // drains vmcnt -> count = 0

    int tk = stok[wv*16 + mr]; if (tk < 0) tk = 0;
    const _Float16* ax = xh + (size_t)tk*H_ + quad*8;

    f4 accg = (f4){0.f,0.f,0.f,0.f}, accu = accg;

    GU_LD(0, 0); GU_LD(1, 1);                 // prologue: 10 in flight

    GU_STEP(0);  GU_STEP(1);  GU_STEP(2);  GU_STEP(3);
    GU_STEP(4);  GU_STEP(5);  GU_STEP(6);  GU_STEP(7);
    GU_STEP(8);  GU_STEP(9);  GU_STEP(10); GU_STEP(11);
    GU_STEP(12); GU_STEP(13); GU_STEP(14); GU_STEP(15);
    GU_STEP(16); GU_STEP(17); GU_STEP(18); GU_STEP(19);
    GU_STEP(20); GU_STEP(21); GU_STEP(22); GU_STEP(23);
    GU_STEP(24); GU_STEP(25); GU_STEP(26); GU_STEP(27);
    GU_STEP(28); GU_STEP(29);
    WAITN(5); GU_CMP(0, 30);                  // tail: no more prefetch
    WAITN(0); GU_CMP(1, 31);

    // epilogue: silu(g)*u*w -> hmid  (C/D: col=mr (i), row=quad*4+r (tok))
    const int icol = bi*16 + mr;
    #pragma unroll
    for (int r = 0; r < 4; r++) {
      int sl = wv*16 + quad*4 + r;
      if (stok[sl] >= 0) {
        float g0 = accg[r];
        float m0 = g0 / (1.f + expf(-g0)) * accu[r] * swt[sl];
        hmid[(size_t)srw[sl]*I_ + icol] = (_Float16)m0;
      }
    }
  }
}
#undef GU_STEP
#undef GU_CMP
#undef GU_LD

// ---------------- down MFMA: scr[t*8+rank, hc*16..+16) = hmid @ Wd ------
// Same barrier-free register-direct structure. Lane's B-frag = Wd column:
// 8 stride-H dwords (instr = 4 rows x 64B chunks), cvt in regs -> no LDS
// transpose, no barriers. grid 64x80 = 5120 blocks x 4 waves, bounds
// (256,6) -> 24 waves/CU. 9 loads/step, 2-deep ring, vmcnt(9), tail 9/0.
#define NKT_D 16

#define DN_LD(SLOT, KT)                                                       \
  do {                                                                        \
    _Pragma("unroll")                                                         \
    for (int j = 0; j < 8; j++)                                               \
      Wd[SLOT][j] = dsrc[(size_t)((KT)*32 + j)*H_];                           \
    Aa[SLOT] = *(const h8*)(ap + (KT)*32);                                    \
  } while (0)

#define DN_CMP(SLOT, KT)                                                      \
  do {                                                                        \
    h8 bf = cvt8s(Wd[SLOT], sdp[(sib0 + ((KT)>>2))*8 + hcb]);                 \
    tot0 = __builtin_amdgcn_mfma_f32_16x16x32_f16(Aa[SLOT], bf, tot0, 0,0,0); \
  } while (0)

#define DN_STEP(KT) do { WAITN(9); DN_CMP((KT)&1, KT); DN_LD((KT)&1, (KT)+2); } while (0)

__global__ __launch_bounds__(256, 6) void down_k(
    const int* __restrict__ wd, const float* __restrict__ sd,
    const int* __restrict__ shwd, const float* __restrict__ shsd,
    const int* __restrict__ cnt, const int* __restrict__ tlist,
    const _Float16* __restrict__ hmid, float* __restrict__ scr)
{
  const int hc = blockIdx.x;                  // h-chunk of 16 (0..63)
  const int eb = blockIdx.y;
  int e, lo, hi;
  eb_decode(eb, cnt, e, lo, hi);
  if (hi <= lo) return;

  const int tid  = threadIdx.x;
  const int lane = tid & 63;
  const int wv   = tid >> 6;                  // token subtile (16 tok)
  const int mr   = lane & 15;
  const int quad = lane >> 4;

  const int* wb; const float* sdp; int sib0;
  if (e < E_) { wb = wd + (size_t)e*I_*H_;        sdp = sd + e*32;  sib0 = 0; }
  else { int hf = e - E_; wb = shwd + (size_t)hf*512*H_; sdp = shsd; sib0 = hf*4; }
  const int hcb = hc >> 3;                    // 128-col scale block

  const int* dsrc = wb + (size_t)(quad*8)*H_ + hc*16 + mr;

  __shared__ int stok[64]; __shared__ int srw[64];

  int Wd[2][8];
  h8  Aa[2];

  for (int base = lo; base < hi; base += 64) {
    __syncthreads();
    if (tid < 64) {
      int slot = base + tid;
      if (slot < hi) {
        int ent = tlist[e*T_ + slot];
        stok[tid] = ent >> 13; srw[tid] = ent & 8191;
      } else { stok[tid] = -1; srw[tid] = 0; }
    }
    __syncthreads();                          // drains vmcnt -> count = 0

    const _Float16* ap = hmid + (size_t)srw[wv*16 + mr]*I_ + quad*8;

    f4 tot0 = (f4){0.f,0.f,0.f,0.f};

    DN_LD(0, 0); DN_LD(1, 1);                 // prologue: 18 in flight

    DN_STEP(0);  DN_STEP(1);  DN_STEP(2);  DN_STEP(3);
    DN_STEP(4);  DN_STEP(5);  DN_STEP(6);  DN_STEP(7);
    DN_STEP(8);  DN_STEP(9);  DN_STEP(10); DN_STEP(11);
    DN_STEP(12); DN_STEP(13);
    WAITN(9); DN_CMP(0, 14);                  // tail
    WAITN(0); DN_CMP(1, 15);

    // epilogue: exactly-once stores to scr[(t*8+rank)][hcol]
    #pragma unroll
    for (int r = 0; r < 4; r++) {
      int sl = wv*16 + quad*4 + r;
      if (stok[sl] >= 0) {
        int t  = stok[sl];
        int sr = srw[sl];
        int rank = (sr < 3072) ? (sr - t*6) : (6 + ((sr - 3072) >> 9));
        scr[(size_t)(t*8 + rank)*H_ + hc*16 + mr] = tot0[r];
      }
    }
  }
}
#undef DN_STEP
#undef DN_CMP
#undef DN_LD

// ---------------- combine: out[t,h] = sum_r scr[t*8+r, h] ---------------
__global__ __launch_bounds__(256) void combine_k(
    const float* __restrict__ scr, float* __restrict__ out)
{
  int i = blockIdx.x*256 + threadIdx.x;       // float4 index over T*H/4
  int t = i >> 8;
  int c = i & 255;
  const float4* base = (const float4*)(scr + (size_t)t*8*H_) + c;
  float4 s = base[0];
  #pragma unroll
  for (int r = 1; r < 8; r++) {
    float4 v = base[(size_t)r*(H_/4)];
    s.x += v.x; s.y += v.y; s.z += v.z; s.w += v.w;
  }
  ((float4*)out)[i] = s;
}

// ---------------- launch ----------------
extern "C" void kernel_launch(void* const* d_in, const int* in_sizes, int n_in,
                              void* d_out, int out_size, void* d_ws, size_t ws_size,
                              hipStream_t stream) {
  (void)in_sizes; (void)n_in; (void)ws_size; (void)out_size;
  const float* x    = (const float*)d_in[0];
  const float* gw   = (const float*)d_in[1];
  const int*   wg   = (const int*  )d_in[2];
  const float* sg   = (const float*)d_in[3];
  const int*   wu   = (const int*  )d_in[4];
  const float* su   = (const float*)d_in[5];
  const int*   wd   = (const int*  )d_in[6];
  const float* sd   = (const float*)d_in[7];
  const int*   shwg = (const int*  )d_in[8];
  const float* shsg = (const float*)d_in[9];
  const int*   shwu = (const int*  )d_in[10];
  const float* shsu = (const float*)d_in[11];
  const int*   shwd = (const int*  )d_in[12];
  const float* shsd = (const float*)d_in[13];
  float* out = (float*)d_out;

  char* ws = (char*)d_ws;
  int*      cnt   = (int*     ) ws;                       // 1 KB
  int*      tlist = (int*     )(ws + 1024);               // 132 KB
  float*    wrow  = (float*   )(ws + 136192);             // 16 KB
  _Float16* hmid  = (_Float16*)(ws + 152576);             // 4 MB
  _Float16* xh    = (_Float16*)(ws + 4346880);            // 1 MB
  float*    scr   = (float*   )(ws + 5395456);            // 16 MB

  hipMemsetAsync(cnt, 0, 1024, stream);
  router_k<<<T_, 64, 0, stream>>>(x, gw, cnt, tlist, wrow, xh);
  gateup_k<<<dim3(32, EB_), 256, 0, stream>>>(xh, wg, sg, wu, su,
                                              shwg, shsg, shwu, shsu,
                                              cnt, tlist, wrow, hmid);
  down_k<<<dim3(64, EB_), 256, 0, stream>>>(wd, sd, shwd, shsd,
                                            cnt, tlist, hmid, scr);
  combine_k<<<512, 256, 0, stream>>>(scr, out);
}

// Round 9
// 546.764 us; speedup vs baseline: 2.0386x; 2.0386x over previous
//
#include <hip/hip_runtime.h>
#include <math.h>
#include <stdint.h>

#define T_   512
#define H_   1024
#define I_   512
#define E_   64
#define K_   6
#define G_   8
#define TG_  3
#define EB_  80      // 64 routed + 16 shared-expert (half x token-eighth) blocks

typedef _Float16 h8 __attribute__((ext_vector_type(8)));
typedef _Float16 h4v __attribute__((ext_vector_type(4)));
typedef float    f4 __attribute__((ext_vector_type(4)));

// ------- router + xh-prep + pseudo-init + wrow table (fused, verified) --
__global__ __launch_bounds__(64) void router_k(
    const float* __restrict__ x, const float* __restrict__ gw,
    int* __restrict__ cnt, int* __restrict__ tlist,
    float* __restrict__ wrow, _Float16* __restrict__ xh)
{
  const int t   = blockIdx.x;
  const int tid = threadIdx.x;
  __shared__ float sx[H_];
  __shared__ float sc[E_];

  for (int h4 = tid; h4 < H_/4; h4 += 64)
    ((float4*)sx)[h4] = ((const float4*)(x + (size_t)t*H_))[h4];
  __syncthreads();

  for (int h4 = tid; h4 < H_/4; h4 += 64) {
    float4 v = ((const float4*)sx)[h4];
    h4v o = { (_Float16)v.x, (_Float16)v.y, (_Float16)v.z, (_Float16)v.w };
    *(h4v*)(xh + (size_t)t*H_ + h4*4) = o;
  }
  if (t < 16) {
    int s  = t*64 + tid;                      // 0..1023
    int e  = 64 + (s >> 9);
    int tt = s & 511;
    tlist[e*T_ + tt] = (tt << 13) | (3072 + s);
    wrow[3072 + s] = 1.0f;
    if (s == 0) { cnt[64] = T_; cnt[65] = T_; }
  }

  const float* wr = gw + (size_t)tid * H_;
  float acc = 0.f;
  for (int h = 0; h < H_; h += 4) {
    float4 xv = *(const float4*)(sx + h);
    float4 wv = *(const float4*)(wr + h);
    acc = fmaf(xv.x, wv.x, acc); acc = fmaf(xv.y, wv.y, acc);
    acc = fmaf(xv.z, wv.z, acc); acc = fmaf(xv.w, wv.w, acc);
  }
  sc[tid] = 1.f / (1.f + expf(-acc));
  __syncthreads();

  if (tid == 0) {
    float gs[G_];
    #pragma unroll
    for (int g = 0; g < G_; g++) {
      float m = sc[g*8];
      #pragma unroll
      for (int j = 1; j < 8; j++) m = fmaxf(m, sc[g*8+j]);
      gs[g] = m;
    }
    unsigned gp = 0;
    for (int r = 0; r < TG_; r++) {
      int best = 0; float bv = -1e30f;
      for (int g = 0; g < G_; g++)
        if (!((gp >> g) & 1) && gs[g] > bv) { bv = gs[g]; best = g; }
      gp |= 1u << best;
    }
    int   eidx[K_]; float ew[K_];
    unsigned long long em = 0ull;
    float wsum = 0.f;
    for (int r = 0; r < K_; r++) {
      int best = 0; float bv = -1e30f;
      for (int e = 0; e < E_; e++) {
        if (!((gp >> (e >> 3)) & 1)) continue;
        if ((em >> e) & 1ull) continue;
        if (sc[e] > bv) { bv = sc[e]; best = e; }
      }
      em |= 1ull << best; eidx[r] = best; ew[r] = bv; wsum += bv;
    }
    const float inv = 2.5f / (wsum + 1e-20f);
    for (int r = 0; r < K_; r++) {
      int e = eidx[r];
      int pos = atomicAdd(&cnt[e], 1);
      tlist[e*T_ + pos] = (t << 13) | (t*K_ + r);   // row = t*6+rank
      wrow[t*K_ + r] = ew[r] * inv;
    }
  }
}

// ---- expert-block descriptor: eb<64 -> routed; eb>=64 -> shared slice ---
__device__ __forceinline__ void eb_decode(int eb, const int* cnt,
                                          int& e, int& lo, int& hi) {
  if (eb < E_) { e = eb; lo = 0; hi = cnt[e]; }
  else { int q = (eb - E_) & 7; e = E_ + ((eb - E_) >> 3); lo = q*64; hi = lo + 64; }
}

// two int4 (8 int32 weights) -> f16 fragment with scale folded (verified)
__device__ __forceinline__ h8 cvt8(int4 a, int4 b, float s) {
  union { _Float16 f[8]; h8 v; } t;
  t.f[0]=(_Float16)((float)a.x*s); t.f[1]=(_Float16)((float)a.y*s);
  t.f[2]=(_Float16)((float)a.z*s); t.f[3]=(_Float16)((float)a.w*s);
  t.f[4]=(_Float16)((float)b.x*s); t.f[5]=(_Float16)((float)b.y*s);
  t.f[6]=(_Float16)((float)b.z*s); t.f[7]=(_Float16)((float)b.w*s);
  return t.v;
}

// ---------------- gate+up MFMA: hmid[row, bi*32..+32) -------------------
// Fat-step + high-occupancy + clean-traffic: 512 thr (8 waves = 4 tok-
// subtiles x 2 i-halves), grid 16x80 = 1280 blocks -> 40 waves/CU avail,
// (512,8) caps 32/CU. Tile 64tok x 32i x {g,u}, full K=1024, BK=64 -> 16
// steps. Per thread/step: 2x int4 W (32B, r5's proven fatness) + 2x h8 A.
// W-ring 3, A-ring 2; r5-style wait/barrier/write/load/compute order;
// steady vmcnt(4), tail 2/0 (positional, derived for this issue order).
#define NKT_G 16

#define GU_W(S, KT) do {                                                      \
    Wr[S][0] = *(const int4*)(wsrc + (KT)*64);                                \
    Wr[S][1] = *(const int4*)(wsrc + (KT)*64 + 4); } while (0)
#define GU_A(S, KT) do {                                                      \
    Aa[S][0] = *(const h8*)(ax + (KT)*64);                                    \
    Aa[S][1] = *(const h8*)(ax + (KT)*64 + 32); } while (0)

#define GU_STEP(KT, WN)                                                       \
  do {                                                                        \
    asm volatile("s_waitcnt vmcnt(" #WN ") lgkmcnt(0)" ::: "memory");         \
    __builtin_amdgcn_sched_barrier(0);                                        \
    __builtin_amdgcn_s_barrier();                                             \
    __builtin_amdgcn_sched_barrier(0);                                        \
    if ((KT) + 1 < NKT_G)                                                     \
      *(h8*)(wdst + (((KT)+1)&1)*9216) =                                      \
          cvt8(Wr[((KT)+1)%3][0], Wr[((KT)+1)%3][1], sv[((KT)+1)>>1]);        \
    if ((KT) + 3 < NKT_G) GU_W(((KT)+3)%3, (KT)+3);                           \
    {                                                                         \
      const char* tb = ldsb + ((KT)&1)*9216;                                  \
      h8 bg0 = *(const h8*)(tb + roA);                                        \
      h8 bg1 = *(const h8*)(tb + roA + 64);                                   \
      h8 bu0 = *(const h8*)(tb + 4608 + roA);                                 \
      h8 bu1 = *(const h8*)(tb + 4608 + roA + 64);                            \
      accg = __builtin_amdgcn_mfma_f32_16x16x32_f16(Aa[(KT)&1][0], bg0, accg, 0,0,0); \
      accg = __builtin_amdgcn_mfma_f32_16x16x32_f16(Aa[(KT)&1][1], bg1, accg, 0,0,0); \
      accu = __builtin_amdgcn_mfma_f32_16x16x32_f16(Aa[(KT)&1][0], bu0, accu, 0,0,0); \
      accu = __builtin_amdgcn_mfma_f32_16x16x32_f16(Aa[(KT)&1][1], bu1, accu, 0,0,0); \
    }                                                                         \
    if ((KT) + 2 < NKT_G) GU_A((KT)&1, (KT)+2);                               \
  } while (0)

__global__ __launch_bounds__(512, 8) void gateup_k(
    const _Float16* __restrict__ xh,
    const int* __restrict__ wg, const float* __restrict__ sg,
    const int* __restrict__ wu, const float* __restrict__ su,
    const int* __restrict__ shwg, const float* __restrict__ shsg,
    const int* __restrict__ shwu, const float* __restrict__ shsu,
    const int* __restrict__ cnt, const int* __restrict__ tlist,
    const float* __restrict__ wrow,
    _Float16* __restrict__ hmid)
{
  const int bi = blockIdx.x;                  // i-chunk of 32 (0..15)
  const int eb = blockIdx.y;
  int e, lo, hi;
  eb_decode(eb, cnt, e, lo, hi);
  if (hi <= lo) return;

  const int tid  = threadIdx.x;
  const int lane = tid & 63;
  const int wv   = tid >> 6;                  // 0..7
  const int mr   = lane & 15;
  const int quad = lane >> 4;
  const int wm   = wv & 3;                    // token subtile (16 tok)
  const int wn   = wv >> 2;                   // i half (16 cols)

  const int *wgb, *wub; const float *sgp, *sup; int sib;
  if (e < E_) {
    wgb = wg + (size_t)e*I_*H_;  wub = wu + (size_t)e*I_*H_;
    sgp = sg + e*32;  sup = su + e*32;  sib = bi >> 2;
  } else {
    int hf = e - E_;
    wgb = shwg + (size_t)hf*512*H_;  wub = shwu + (size_t)hf*512*H_;
    sgp = shsg;  sup = shsu;  sib = hf*4 + (bi >> 2);
  }

  // staging role: threads 0..255 stage gate, 256..511 stage up
  const int smat = tid >> 8;
  const int sr   = (tid >> 3) & 31;           // tile row (i)
  const int seg  = tid & 7;                   // 8-int segment of 64-int step
  const int* wsrc = (smat ? wub : wgb) + (size_t)(bi*32 + sr)*H_ + seg*8;
  const float* ssc = (smat ? sup : sgp) + sib*8;
  float sv[8];
  #pragma unroll
  for (int b = 0; b < 8; b++) sv[b] = ssc[b];

  __shared__ _Float16 wlds[2*2*32*72];        // [buf][mat][row][72] 18.4KB
  __shared__ int stok[64]; __shared__ int srw[64]; __shared__ float swt[64];
  char* ldsb = (char*)wlds;
  char* wdst = ldsb + smat*4608 + sr*144 + seg*16;
  const int roA = (wn*16 + mr)*144 + quad*16;

  int4 Wr[3][2];
  h8   Aa[2][2];

  for (int base = lo; base < hi; base += 64) {
    __syncthreads();
    if (tid < 64) {
      int slot = base + tid;
      if (slot < hi) {
        int ent = tlist[e*T_ + slot];
        stok[tid] = ent >> 13; srw[tid] = ent & 8191;
        swt[tid]  = wrow[ent & 8191];
      } else { stok[tid] = -1; srw[tid] = 0; swt[tid] = 0.f; }
    }
    __syncthreads();                          // drains all counters

    int tk = stok[wm*16 + mr]; if (tk < 0) tk = 0;
    const _Float16* ax = xh + (size_t)tk*H_ + quad*8;

    f4 accg = (f4){0.f,0.f,0.f,0.f}, accu = accg;

    // prologue: W0 A0 W1 A1 W2 = 10 loads; wait W0 -> vmcnt(8); write buf0
    GU_W(0, 0); GU_A(0, 0); GU_W(1, 1); GU_A(1, 1); GU_W(2, 2);
    asm volatile("s_waitcnt vmcnt(8)" ::: "memory");
    __builtin_amdgcn_sched_barrier(0);
    *(h8*)(wdst) = cvt8(Wr[0][0], Wr[0][1], sv[0]);

    GU_STEP(0,4);  GU_STEP(1,4);  GU_STEP(2,4);  GU_STEP(3,4);
    GU_STEP(4,4);  GU_STEP(5,4);  GU_STEP(6,4);  GU_STEP(7,4);
    GU_STEP(8,4);  GU_STEP(9,4);  GU_STEP(10,4); GU_STEP(11,4);
    GU_STEP(12,4); GU_STEP(13,4); GU_STEP(14,2); GU_STEP(15,0);

    // epilogue: silu(g)*u*w -> hmid  (C/D: col=mr (i), row=quad*4+r (tok))
    const int icol = bi*32 + wn*16 + mr;
    #pragma unroll
    for (int r = 0; r < 4; r++) {
      int sl = wm*16 + quad*4 + r;
      if (stok[sl] >= 0) {
        float g0 = accg[r];
        float m0 = g0 / (1.f + expf(-g0)) * accu[r] * swt[sl];
        hmid[(size_t)srw[sl]*I_ + icol] = (_Float16)m0;
      }
    }
  }
}
#undef GU_STEP
#undef GU_A
#undef GU_W

// ---------------- down MFMA: scr[t*8+rank, hc*32..+32) = hmid @ Wd ------
// Same fat-step structure: 256 thr (4 tok-subtile waves), grid 32x80 =
// 2560 blocks -> 40 waves/CU avail, (256,8) caps 32/CU. Tile 64tok x 32h,
// K=512, BK=64 -> 8 steps. Per thread/step: 4x int2 W (32B, coalesced
// 128B row-segments, reg-transposed into [32h][72] LDS) + 2x h8 A.
// Steady vmcnt(6), tail 2/0. scr stores = full 128B lines (no RFO).
#define NKT_D 8

#define DN_W(S, KT) do {                                                      \
    Wr[S][0] = *(const int2*)(dsrc + (size_t)((KT)*64 + 0)*H_);               \
    Wr[S][1] = *(const int2*)(dsrc + (size_t)((KT)*64 + 1)*H_);               \
    Wr[S][2] = *(const int2*)(dsrc + (size_t)((KT)*64 + 2)*H_);               \
    Wr[S][3] = *(const int2*)(dsrc + (size_t)((KT)*64 + 3)*H_); } while (0)
#define DN_A(S, KT) do {                                                      \
    Aa[S][0] = *(const h8*)(ap + (KT)*64);                                    \
    Aa[S][1] = *(const h8*)(ap + (KT)*64 + 32); } while (0)
#define DN_WRT(S, BUF, SC) do {                                               \
    h4v v0 = { (_Float16)((float)Wr[S][0].x*(SC)),                            \
               (_Float16)((float)Wr[S][1].x*(SC)),                            \
               (_Float16)((float)Wr[S][2].x*(SC)),                            \
               (_Float16)((float)Wr[S][3].x*(SC)) };                          \
    h4v v1 = { (_Float16)((float)Wr[S][0].y*(SC)),                            \
               (_Float16)((float)Wr[S][1].y*(SC)),                            \
               (_Float16)((float)Wr[S][2].y*(SC)),                            \
               (_Float16)((float)Wr[S][3].y*(SC)) };                          \
    *(h4v*)(ddst + (BUF)*4608)       = v0;                                    \
    *(h4v*)(ddst + (BUF)*4608 + 144) = v1; } while (0)

#define DN_STEP(KT, WN)                                                       \
  do {                                                                        \
    asm volatile("s_waitcnt vmcnt(" #WN ") lgkmcnt(0)" ::: "memory");         \
    __builtin_amdgcn_sched_barrier(0);                                        \
    __builtin_amdgcn_s_barrier();                                             \
    __builtin_amdgcn_sched_barrier(0);                                        \
    if ((KT) + 1 < NKT_D) DN_WRT(((KT)+1)%3, ((KT)+1)&1, sdv[((KT)+1)>>1]);   \
    if ((KT) + 3 < NKT_D) DN_W(((KT)+3)%3, (KT)+3);                           \
    {                                                                         \
      const char* tb = ldsb + ((KT)&1)*4608;                                  \
      h8 b00 = *(const h8*)(tb + (     mr)*144 + quad*16);                    \
      h8 b01 = *(const h8*)(tb + (     mr)*144 + quad*16 + 64);               \
      h8 b10 = *(const h8*)(tb + (16 + mr)*144 + quad*16);                    \
      h8 b11 = *(const h8*)(tb + (16 + mr)*144 + quad*16 + 64);               \
      tot0 = __builtin_amdgcn_mfma_f32_16x16x32_f16(Aa[(KT)&1][0], b00, tot0, 0,0,0); \
      tot0 = __builtin_amdgcn_mfma_f32_16x16x32_f16(Aa[(KT)&1][1], b01, tot0, 0,0,0); \
      tot1 = __builtin_amdgcn_mfma_f32_16x16x32_f16(Aa[(KT)&1][0], b10, tot1, 0,0,0); \
      tot1 = __builtin_amdgcn_mfma_f32_16x16x32_f16(Aa[(KT)&1][1], b11, tot1, 0,0,0); \
    }                                                                         \
    if ((KT) + 2 < NKT_D) DN_A((KT)&1, (KT)+2);                               \
  } while (0)

__global__ __launch_bounds__(256, 8) void down_k(
    const int* __restrict__ wd, const float* __restrict__ sd,
    const int* __restrict__ shwd, const float* __restrict__ shsd,
    const int* __restrict__ cnt, const int* __restrict__ tlist,
    const _Float16* __restrict__ hmid, float* __restrict__ scr)
{
  const int hc = blockIdx.x;                  // h-chunk of 32 (0..31)
  const int eb = blockIdx.y;
  int e, lo, hi;
  eb_decode(eb, cnt, e, lo, hi);
  if (hi <= lo) return;

  const int tid  = threadIdx.x;
  const int lane = tid & 63;
  const int wv   = tid >> 6;                  // token subtile (16 tok)
  const int mr   = lane & 15;
  const int quad = lane >> 4;

  const int* wb; const float* sdp; int sib0;
  if (e < E_) { wb = wd + (size_t)e*I_*H_;        sdp = sd + e*32;  sib0 = 0; }
  else { int hf = e - E_; wb = shwd + (size_t)hf*512*H_; sdp = shsd; sib0 = hf*4; }
  float sdv[4];
  #pragma unroll
  for (int ib = 0; ib < 4; ib++) sdv[ib] = sdp[(sib0+ib)*8 + (hc >> 2)];

  // staging: ig = tid>>4 (4-row i group), hp = tid&15 (2 h-cols)
  const int ig = tid >> 4;
  const int hp = tid & 15;
  const int* dsrc = wb + (size_t)(ig*4)*H_ + hc*32 + hp*2;

  __shared__ _Float16 wlds[2*32*72];          // [buf][h][72] 9.2KB
  __shared__ int stok[64]; __shared__ int srw[64];
  char* ldsb = (char*)wlds;
  char* ddst = ldsb + (hp*2)*144 + ig*8;

  int2 Wr[3][4];
  h8   Aa[2][2];

  for (int base = lo; base < hi; base += 64) {
    __syncthreads();
    if (tid < 64) {
      int slot = base + tid;
      if (slot < hi) {
        int ent = tlist[e*T_ + slot];
        stok[tid] = ent >> 13; srw[tid] = ent & 8191;
      } else { stok[tid] = -1; srw[tid] = 0; }
    }
    __syncthreads();                          // drains all counters

    const _Float16* ap = hmid + (size_t)srw[wv*16 + mr]*I_ + quad*8;

    f4 tot0 = (f4){0.f,0.f,0.f,0.f}, tot1 = tot0;

    // prologue: W0(4) A0(2) W1(4) A1(2) W2(4) = 16; wait W0 -> vmcnt(12)
    DN_W(0, 0); DN_A(0, 0); DN_W(1, 1); DN_A(1, 1); DN_W(2, 2);
    asm volatile("s_waitcnt vmcnt(12)" ::: "memory");
    __builtin_amdgcn_sched_barrier(0);
    DN_WRT(0, 0, sdv[0]);

    DN_STEP(0,6); DN_STEP(1,6); DN_STEP(2,6); DN_STEP(3,6);
    DN_STEP(4,6); DN_STEP(5,6); DN_STEP(6,2); DN_STEP(7,0);

    // epilogue: exactly-once stores to scr[(t*8+rank)][hcol]
    #pragma unroll
    for (int r = 0; r < 4; r++) {
      int sl = wv*16 + quad*4 + r;
      if (stok[sl] >= 0) {
        int t  = stok[sl];
        int sr = srw[sl];
        int rank = (sr < 3072) ? (sr - t*6) : (6 + ((sr - 3072) >> 9));
        float* dst = scr + (size_t)(t*8 + rank)*H_ + hc*32 + mr;
        dst[0]  = tot0[r];
        dst[16] = tot1[r];
      }
    }
  }
}
#undef DN_STEP
#undef DN_WRT
#undef DN_A
#undef DN_W

// ---------------- combine: out[t,h] = sum_r scr[t*8+r, h] ---------------
__global__ __launch_bounds__(256) void combine_k(
    const float* __restrict__ scr, float* __restrict__ out)
{
  int i = blockIdx.x*256 + threadIdx.x;       // float4 index over T*H/4
  int t = i >> 8;
  int c = i & 255;
  const float4* base = (const float4*)(scr + (size_t)t*8*H_) + c;
  float4 s = base[0];
  #pragma unroll
  for (int r = 1; r < 8; r++) {
    float4 v = base[(size_t)r*(H_/4)];
    s.x += v.x; s.y += v.y; s.z += v.z; s.w += v.w;
  }
  ((float4*)out)[i] = s;
}

// ---------------- launch ----------------
extern "C" void kernel_launch(void* const* d_in, const int* in_sizes, int n_in,
                              void* d_out, int out_size, void* d_ws, size_t ws_size,
                              hipStream_t stream) {
  (void)in_sizes; (void)n_in; (void)ws_size; (void)out_size;
  const float* x    = (const float*)d_in[0];
  const float* gw   = (const float*)d_in[1];
  const int*   wg   = (const int*  )d_in[2];
  const float* sg   = (const float*)d_in[3];
  const int*   wu   = (const int*  )d_in[4];
  const float* su   = (const float*)d_in[5];
  const int*   wd   = (const int*  )d_in[6];
  const float* sd   = (const float*)d_in[7];
  const int*   shwg = (const int*  )d_in[8];
  const float* shsg = (const float*)d_in[9];
  const int*   shwu = (const int*  )d_in[10];
  const float* shsu = (const float*)d_in[11];
  const int*   shwd = (const int*  )d_in[12];
  const float* shsd = (const float*)d_in[13];
  float* out = (float*)d_out;

  char* ws = (char*)d_ws;
  int*      cnt   = (int*     ) ws;                       // 1 KB
  int*      tlist = (int*     )(ws + 1024);               // 132 KB
  float*    wrow  = (float*   )(ws + 136192);             // 16 KB
  _Float16* hmid  = (_Float16*)(ws + 152576);             // 4 MB
  _Float16* xh    = (_Float16*)(ws + 4346880);            // 1 MB
  float*    scr   = (float*   )(ws + 5395456);            // 16 MB

  hipMemsetAsync(cnt, 0, 1024, stream);
  router_k<<<T_, 64, 0, stream>>>(x, gw, cnt, tlist, wrow, xh);
  gateup_k<<<dim3(16, EB_), 512, 0, stream>>>(xh, wg, sg, wu, su,
                                              shwg, shsg, shwu, shsu,
                                              cnt, tlist, wrow, hmid);
  down_k<<<dim3(32, EB_), 256, 0, stream>>>(wd, sd, shwd, shsd,
                                            cnt, tlist, hmid, scr);
  combine_k<<<512, 256, 0, stream>>>(scr, out);
}